// Round 1
// baseline (105.324 us; speedup 1.0000x reference)
//
#include <hip/hip_runtime.h>

// Erosion2d: 3x3 windowed min, stride 1, pad with +huge (never selected since
// inputs are N(0,1) and reference pad is 1e9).
// Shapes: N=16, C=64, H=256, W=256 (fp32 in, fp32 out).

#define HH 256
#define WW 256
#define PADV 1e30f

__device__ __forceinline__ float4 hmin_row(const float* __restrict__ row, int x0) {
    // x0 is a multiple of 4 in [0, 252]
    float4 v = *reinterpret_cast<const float4*>(row + x0);
    float left  = (x0 > 0)        ? row[x0 - 1] : PADV;
    float right = (x0 + 4 < WW)   ? row[x0 + 4] : PADV;
    float4 h;
    h.x = fminf(left, fminf(v.x, v.y));
    h.y = fminf(v.x,  fminf(v.y, v.z));
    h.z = fminf(v.y,  fminf(v.z, v.w));
    h.w = fminf(v.z,  fminf(v.w, right));
    return h;
}

__global__ __launch_bounds__(256)
void erosion3x3_kernel(const float* __restrict__ in, float* __restrict__ out) {
    // One thread computes a 4(rows) x 4(cols) output patch.
    // Block: 256 threads = 64 x-quads (full row of W=256) x 4 row-quads (16 rows).
    // Grid: planes(16*64=1024) * (256/16 = 16 row-tiles) = 16384 blocks.
    const int tid  = threadIdx.x;
    const int xq   = tid & 63;        // x-quad index: x0 = 4*xq
    const int ryt  = tid >> 6;        // row-quad within block: 0..3
    const int b    = blockIdx.x;
    const int plane   = b >> 4;       // 0..1023  (n*64 + c)
    const int ytileBl = b & 15;       // 16-row tile within plane

    const int y0 = ytileBl * 16 + ryt * 4;
    const int x0 = xq * 4;

    const float* __restrict__ base  = in  + (size_t)plane * (HH * WW);
    float*       __restrict__ obase = out + (size_t)plane * (HH * WW);

    float4 hm_prev, hm_cur, hm_next;

    if (y0 > 0) hm_prev = hmin_row(base + (size_t)(y0 - 1) * WW, x0);
    else        hm_prev = make_float4(PADV, PADV, PADV, PADV);

    hm_cur = hmin_row(base + (size_t)y0 * WW, x0);

#pragma unroll
    for (int i = 0; i < 4; ++i) {
        const int yn = y0 + 1 + i;
        if (yn < HH) hm_next = hmin_row(base + (size_t)yn * WW, x0);
        else         hm_next = make_float4(PADV, PADV, PADV, PADV);

        float4 o;
        o.x = fminf(hm_prev.x, fminf(hm_cur.x, hm_next.x));
        o.y = fminf(hm_prev.y, fminf(hm_cur.y, hm_next.y));
        o.z = fminf(hm_prev.z, fminf(hm_cur.z, hm_next.z));
        o.w = fminf(hm_prev.w, fminf(hm_cur.w, hm_next.w));

        *reinterpret_cast<float4*>(obase + (size_t)(y0 + i) * WW + x0) = o;

        hm_prev = hm_cur;
        hm_cur  = hm_next;
    }
}

extern "C" void kernel_launch(void* const* d_in, const int* in_sizes, int n_in,
                              void* d_out, int out_size, void* d_ws, size_t ws_size,
                              hipStream_t stream) {
    const float* x = (const float*)d_in[0];
    float* out = (float*)d_out;

    // 16*64 planes, each 256x256; 16 rows per block.
    const int planes = 16 * 64;
    const int blocks = planes * (HH / 16);
    erosion3x3_kernel<<<blocks, 256, 0, stream>>>(x, out);
}